// Round 4
// baseline (225.750 us; speedup 1.0000x reference)
//
#include <hip/hip_runtime.h>
#include <hip/hip_bf16.h>
#include <math.h>

// ---------------- types ----------------
typedef short s16x8 __attribute__((ext_vector_type(8)));
typedef float f32x4 __attribute__((ext_vector_type(4)));

// ---------------- fp32 <-> bf16 ----------------
__device__ inline unsigned short f2bf(float x) {
    unsigned int u = __float_as_uint(x);
    unsigned int r = (u + 0x7fffu + ((u >> 16) & 1u)) >> 16;
    return (unsigned short)r;
}
__device__ inline float bf2f(unsigned short u) {
    return __uint_as_float(((unsigned int)u) << 16);
}

// fast tanh: 1 - 2/(exp(2x)+1); saturates correctly at +-inf
__device__ inline float fast_tanh(float x) {
    float e = __expf(2.0f * x);
    return 1.0f - 2.0f * __builtin_amdgcn_rcpf(e + 1.0f);
}

// -------- fused: cvt x, cvt W_ih, pack W_lin -> bf16, zero accumulators -----
__global__ void cvtprep_kernel(const float* __restrict__ x,
                               const float* __restrict__ W_ih,
                               const float* __restrict__ W_lin,
                               unsigned short* __restrict__ xb,
                               unsigned short* __restrict__ wb,
                               unsigned short* __restrict__ wlb,
                               float* __restrict__ zbase) {
    int blk = blockIdx.x;
    int tid = threadIdx.x;
    if (blk < 16384) {
        int i = blk * 256 + tid;
        float4 v = ((const float4*)x)[i];
        ushort4 o; o.x = f2bf(v.x); o.y = f2bf(v.y); o.z = f2bf(v.z); o.w = f2bf(v.w);
        ((ushort4*)xb)[i] = o;
    } else if (blk < 20480) {
        int i = (blk - 16384) * 256 + tid;
        float4 v = ((const float4*)W_ih)[i];
        ushort4 o; o.x = f2bf(v.x); o.y = f2bf(v.y); o.z = f2bf(v.z); o.w = f2bf(v.w);
        ((ushort4*)wb)[i] = o;
    } else if (blk < 20626) {
        int idx = (blk - 20480) * 256 + tid;   // 16*2336 = 37376
        int c = idx / 2336, k = idx - c * 2336;
        float v = (c < 10 && k < 2318) ? W_lin[c * 2318 + k] : 0.f;
        wlb[idx] = f2bf(v);
    } else {
        // zero pooled_t (45*8192) + linp (8192*10) = 450560 floats = 112640 f4
        int i = (blk - 20626) * 256 + tid;
        ((float4*)zbase)[i] = float4{0.f, 0.f, 0.f, 0.f};
    }
}

// ---------------- GEMM: tanh(x @ W_ih^T + b), fused pool + linear partials ---
// Main loop unchanged from round 2 (256x256 tile, BK=64, balanced 4-phase,
// counted vmcnt, setprio, XCD map 4rblk x 8cblk).
// Epilogue: NO Hb write. tanh'd bf16 tile -> reused 128KB LDS (8-short blocks
// XOR-swizzled by row&7), then (a) partial 45-wide window sums -> atomicAdd
// pooled_t, (b) 16 MFMAs/wave vs wlb -> atomicAdd linp (K=2048 linear part).

#define MFMA_(a, b, c) __builtin_amdgcn_mfma_f32_16x16x32_bf16(a, b, c, 0, 0, 0)

__device__ inline s16x8 frag_ld(const unsigned short* hbase, int row, int ksub, int quad) {
    int slot = (ksub * 4 + quad) ^ (row & 7);
    return *(const s16x8*)(hbase + row * 64 + slot * 8);
}

// stage one 8KB unit: 64 rows x 64 cols bf16, 1x16B load per thread
__device__ inline void stage_u(const unsigned short* __restrict__ gmat, int half,
                               int rowoff, int kt, unsigned short* lmat, int tid) {
    int r = tid >> 3, s = tid & 7;
    int lr = rowoff + r;
    int ks = (s ^ (lr & 7)) << 3;
    const unsigned short* gp = gmat + (size_t)(half * 128 + lr) * 2048 + kt * 64 + ks;
    __builtin_amdgcn_global_load_lds(
        (const __attribute__((address_space(1))) void*)gp,
        (__attribute__((address_space(3))) void*)(lmat + half * 8192 + lr * 64 + s * 8),
        16, 0, 0);
}

#define LOAD_B(ks)                                                       \
    b0 = frag_ld(Bh, bco +  0 + mrow, (ks), quad);                       \
    b1 = frag_ld(Bh, bco + 16 + mrow, (ks), quad);                       \
    b2 = frag_ld(Bh, bco + 32 + mrow, (ks), quad);                       \
    b3 = frag_ld(Bh, bco + 48 + mrow, (ks), quad);

#define LOAD_A(h, ks)                                                    \
    af0 = frag_ld(Ah, (h) * 64 +  0 + mrow, (ks), quad);                 \
    af1 = frag_ld(Ah, (h) * 64 + 16 + mrow, (ks), quad);                 \
    af2 = frag_ld(Ah, (h) * 64 + 32 + mrow, (ks), quad);                 \
    af3 = frag_ld(Ah, (h) * 64 + 48 + mrow, (ks), quad);

#define MFMA_H(hh)                                                       \
    acc[(hh)*4 + 0][0] = MFMA_(af0, b0, acc[(hh)*4 + 0][0]);             \
    acc[(hh)*4 + 0][1] = MFMA_(af0, b1, acc[(hh)*4 + 0][1]);             \
    acc[(hh)*4 + 0][2] = MFMA_(af0, b2, acc[(hh)*4 + 0][2]);             \
    acc[(hh)*4 + 0][3] = MFMA_(af0, b3, acc[(hh)*4 + 0][3]);             \
    acc[(hh)*4 + 1][0] = MFMA_(af1, b0, acc[(hh)*4 + 1][0]);             \
    acc[(hh)*4 + 1][1] = MFMA_(af1, b1, acc[(hh)*4 + 1][1]);             \
    acc[(hh)*4 + 1][2] = MFMA_(af1, b2, acc[(hh)*4 + 1][2]);             \
    acc[(hh)*4 + 1][3] = MFMA_(af1, b3, acc[(hh)*4 + 1][3]);             \
    acc[(hh)*4 + 2][0] = MFMA_(af2, b0, acc[(hh)*4 + 2][0]);             \
    acc[(hh)*4 + 2][1] = MFMA_(af2, b1, acc[(hh)*4 + 2][1]);             \
    acc[(hh)*4 + 2][2] = MFMA_(af2, b2, acc[(hh)*4 + 2][2]);             \
    acc[(hh)*4 + 2][3] = MFMA_(af2, b3, acc[(hh)*4 + 2][3]);             \
    acc[(hh)*4 + 3][0] = MFMA_(af3, b0, acc[(hh)*4 + 3][0]);             \
    acc[(hh)*4 + 3][1] = MFMA_(af3, b1, acc[(hh)*4 + 3][1]);             \
    acc[(hh)*4 + 3][2] = MFMA_(af3, b2, acc[(hh)*4 + 3][2]);             \
    acc[(hh)*4 + 3][3] = MFMA_(af3, b3, acc[(hh)*4 + 3][3]);

#define PHASE_CORE(hh)                                                   \
    __builtin_amdgcn_s_barrier();                                        \
    asm volatile("s_waitcnt lgkmcnt(0)" ::: "memory");                   \
    __builtin_amdgcn_s_setprio(1);                                       \
    MFMA_H(hh);                                                          \
    __builtin_amdgcn_s_setprio(0);

__global__ __launch_bounds__(512) void gemm_tanh_kernel(
    const unsigned short* __restrict__ A, const unsigned short* __restrict__ Bm,
    const float* __restrict__ b_ih, const float* __restrict__ b_hh,
    const unsigned short* __restrict__ Wl,
    float* __restrict__ pooled_t, float* __restrict__ linp)
{
    __shared__ __align__(16) unsigned short lds[2][2][16384];  // 128 KB

    const int tid  = threadIdx.x;
    const int lane = tid & 63;
    const int wave = tid >> 6;
    const int wgid = blockIdx.x;
    const int xcd  = wgid & 7;
    const int idx  = wgid >> 3;          // 0..31
    const int rblk = xcd * 4 + (idx & 3);
    const int cblk = idx >> 2;           // 0..7
    const int row0 = rblk * 256;
    const int col0 = cblk * 256;
    const int wm   = wave >> 2;   // 0..1 : A half / 128-row block
    const int wn   = wave & 3;    // 0..3 : 64-col block
    const int quad = lane >> 4;
    const int mrow = lane & 15;
    const int NT   = 32;          // K tiles of 64

    const unsigned short* Ag = A  + (size_t)row0 * 2048;
    const unsigned short* Bg = Bm + (size_t)col0 * 2048;

    f32x4 acc[8][4];
#pragma unroll
    for (int i = 0; i < 8; ++i)
#pragma unroll
        for (int j = 0; j < 4; ++j) acc[i][j] = f32x4{0.f, 0.f, 0.f, 0.f};

    stage_u(Ag, 0, 0,  0, lds[0][0], tid);  stage_u(Ag, 0, 64, 0, lds[0][0], tid);
    stage_u(Ag, 1, 0,  0, lds[0][0], tid);  stage_u(Ag, 1, 64, 0, lds[0][0], tid);
    stage_u(Bg, 0, 0,  0, lds[0][1], tid);  stage_u(Bg, 0, 64, 0, lds[0][1], tid);
    stage_u(Bg, 1, 0,  0, lds[0][1], tid);  stage_u(Bg, 1, 64, 0, lds[0][1], tid);
    stage_u(Bg, 0, 0,  1, lds[1][1], tid);  stage_u(Bg, 0, 64, 1, lds[1][1], tid);
    stage_u(Ag, 0, 0,  1, lds[1][0], tid);  stage_u(Ag, 1, 0,  1, lds[1][0], tid);
    asm volatile("s_waitcnt vmcnt(4)" ::: "memory");  // tile0 resident
    __builtin_amdgcn_s_barrier();

    for (int t = 0; t < NT; ++t) {
        const int buf = t & 1;
        unsigned short* LA  = lds[buf][0];
        unsigned short* LB  = lds[buf][1];
        unsigned short* NLA = lds[buf ^ 1][0];
        unsigned short* NLB = lds[buf ^ 1][1];
        const unsigned short* Ah = LA + wm * 8192;
        const unsigned short* Bh = LB + (wn >> 1) * 8192;
        const int bco = (wn & 1) * 64;

        s16x8 b0, b1, b2, b3;
        s16x8 af0, af1, af2, af3;

        // ===== phase 1: B ks0 + A lo ks0 | stage t+1 A-bot + t+1 B-h1 =====
        LOAD_B(0);
        LOAD_A(0, 0);
        if (t + 1 < NT) {
            stage_u(Ag, 0, 64, t + 1, NLA, tid);
            stage_u(Ag, 1, 64, t + 1, NLA, tid);
            stage_u(Bg, 1, 0,  t + 1, NLB, tid);
            stage_u(Bg, 1, 64, t + 1, NLB, tid);
        }
        asm volatile("s_waitcnt lgkmcnt(4)" ::: "memory");  // B ks0 done
        PHASE_CORE(0);
        __builtin_amdgcn_s_barrier();

        // ===== phase 2: A hi ks0 =====
        LOAD_A(1, 0);
        PHASE_CORE(1);
        __builtin_amdgcn_s_barrier();

        // ===== phase 3: B ks1 + A lo ks1 =====
        LOAD_B(1);
        LOAD_A(0, 1);
        asm volatile("s_waitcnt lgkmcnt(4)" ::: "memory");  // B ks1 done
        PHASE_CORE(0);
        __builtin_amdgcn_s_barrier();

        // ===== phase 4: A hi ks1 | stage t+2 B-h0 + t+2 A-top; boundary =====
        LOAD_A(1, 1);
        if (t + 2 < NT) {
            stage_u(Bg, 0, 0,  t + 2, LB, tid);
            stage_u(Bg, 0, 64, t + 2, LB, tid);
            stage_u(Ag, 0, 0,  t + 2, LA, tid);
            stage_u(Ag, 1, 0,  t + 2, LA, tid);
        }
        PHASE_CORE(1);
        if (t + 2 < NT) {
            asm volatile("s_waitcnt vmcnt(4)" ::: "memory");   // t+1 resident
        } else if (t + 1 < NT) {
            asm volatile("s_waitcnt vmcnt(0)" ::: "memory");   // final drain
        }
        __builtin_amdgcn_s_barrier();
    }

    // ===================== fused epilogue (no Hb) =====================
    __syncthreads();                       // all LDS reads of K-loop done
    unsigned short* T = &lds[0][0][0];     // 256x256 bf16 tile, row stride 256,
                                           // 8-short blocks XOR'd by (row&7)
    float bias[4];
#pragma unroll
    for (int j = 0; j < 4; ++j) {
        int gc = col0 + wn * 64 + j * 16 + mrow;
        bias[j] = b_ih[gc] + b_hh[gc];
    }
#pragma unroll
    for (int i = 0; i < 8; ++i) {
#pragma unroll
        for (int rr = 0; rr < 4; ++rr) {
            int lrow = wm * 128 + i * 16 + quad * 4 + rr;
#pragma unroll
            for (int j = 0; j < 4; ++j) {
                int lcol = wn * 64 + j * 16 + mrow;
                float v = acc[i][j][rr] + bias[j];
                int cb = (lcol >> 3) ^ (lrow & 7);
                T[lrow * 256 + cb * 8 + (lcol & 7)] = f2bf(fast_tanh(v));
            }
        }
    }
    __syncthreads();

    // (a) pooling partials: features overlapping [col0, col0+256)
    int f0 = col0 / 45;
    for (int o = tid; o < 1792; o += 512) {       // 256 rows x 7 slots
        int lrow = o / 7;
        int fi = o - lrow * 7;
        int f = f0 + fi;
        if (f < 45) {
            int wsb = f * 45, web = wsb + 45;
            int s = (wsb > col0) ? wsb : col0;
            int e = (web < col0 + 256) ? web : (col0 + 256);
            if (s < e) {
                float sum = 0.f;
                for (int c = s - col0; c < e - col0; ++c) {
                    int cb = (c >> 3) ^ (lrow & 7);
                    sum += bf2f(T[lrow * 256 + cb * 8 + (c & 7)]);
                }
                atomicAdd(&pooled_t[f * 8192 + row0 + lrow], sum);
            }
        }
    }

    // (b) linear partials: T(256x256) @ Wl[:, col0:col0+256]^T -> linp
    f32x4 la = f32x4{0.f, 0.f, 0.f, 0.f};
    f32x4 lb = f32x4{0.f, 0.f, 0.f, 0.f};
    const int lr0 = wave * 32 + mrow;        // M-tile 2*wave
    const int lr1 = lr0 + 16;                // M-tile 2*wave+1
#pragma unroll
    for (int ks = 0; ks < 8; ++ks) {
        int c = ks * 32 + quad * 8;
        s16x8 bfrag = *(const s16x8*)(Wl + (size_t)mrow * 2336 + col0 + c);
        int cb0 = (c >> 3) ^ (lr0 & 7);
        s16x8 a0 = *(const s16x8*)(T + lr0 * 256 + cb0 * 8);
        la = MFMA_(a0, bfrag, la);
        int cb1 = (c >> 3) ^ (lr1 & 7);
        s16x8 a1 = *(const s16x8*)(T + lr1 * 256 + cb1 * 8);
        lb = MFMA_(a1, bfrag, lb);
    }
    if (mrow < 10) {
#pragma unroll
        for (int rr = 0; rr < 4; ++rr) {
            atomicAdd(&linp[(size_t)(row0 + wave * 32 + quad * 4 + rr) * 10 + mrow], la[rr]);
            atomicAdd(&linp[(size_t)(row0 + wave * 32 + 16 + quad * 4 + rr) * 10 + mrow], lb[rr]);
        }
    }
}

// ---------------- per-(feature,chunk) local dual prefix sum ------------------
// 360 blocks = 45 feats x 8 chunks of 1024. pooled_t holds RAW window sums
// (from atomics); scale by 1/45 here.
__global__ __launch_bounds__(256) void scan_kernel(
    const float* __restrict__ pooled_t,
    float* __restrict__ cs_t, float* __restrict__ cs2_t,
    float* __restrict__ sums1, float* __restrict__ sums2) {
    __shared__ float t1[256], t2[256];
    int f  = blockIdx.x >> 3;
    int ch = blockIdx.x & 7;
    int tid = threadIdx.x;
    const float S = 1.0f / 45.0f;
    const float* p = pooled_t + f * 8192 + ch * 1024;
    float4 v = ((const float4*)p)[tid];
    v.x *= S; v.y *= S; v.z *= S; v.w *= S;
    float q1[4], q2[4];
    q1[0] = v.x;          q2[0] = v.x * v.x;
    q1[1] = q1[0] + v.y;  q2[1] = q2[0] + v.y * v.y;
    q1[2] = q1[1] + v.z;  q2[2] = q2[1] + v.z * v.z;
    q1[3] = q1[2] + v.w;  q2[3] = q2[2] + v.w * v.w;
    float s1 = q1[3], s2 = q2[3];
    t1[tid] = s1; t2[tid] = s2;
    __syncthreads();
    for (int d = 1; d < 256; d <<= 1) {
        float a1 = (tid >= d) ? t1[tid - d] : 0.f;
        float a2 = (tid >= d) ? t2[tid - d] : 0.f;
        __syncthreads();
        t1[tid] += a1; t2[tid] += a2;
        __syncthreads();
    }
    float r1 = t1[tid] - s1, r2 = t2[tid] - s2;  // exclusive offsets
    float4 o1, o2;
    o1.x = r1 + q1[0]; o1.y = r1 + q1[1]; o1.z = r1 + q1[2]; o1.w = r1 + q1[3];
    o2.x = r2 + q2[0]; o2.y = r2 + q2[1]; o2.z = r2 + q2[2]; o2.w = r2 + q2[3];
    ((float4*)(cs_t  + f * 8192 + ch * 1024))[tid] = o1;
    ((float4*)(cs2_t + f * 8192 + ch * 1024))[tid] = o2;
    if (tid == 255) {
        sums1[f * 8 + ch] = t1[255];
        sums2[f * 8 + ch] = t2[255];
    }
}

// ---------------- final-lite: est MFMA (K=288) + linp + softmax --------------
// 256 blocks x 128 thr (2 waves x 16 rows = 32 rows/block).
#define ESTRIDE 290
__global__ __launch_bounds__(128) void final_kernel(
    const float* __restrict__ cs_t, const float* __restrict__ cs2_t,
    const float* __restrict__ sums1, const float* __restrict__ sums2,
    const unsigned short* __restrict__ Wb, const float* __restrict__ linp,
    const float* __restrict__ b_lin, float* __restrict__ out) {
    __shared__ unsigned short Es[32 * ESTRIDE];  // 18.1 KB
    __shared__ float eb1[45 * 8], eb2[45 * 8];   // 2.8 KB chunk bases
    __shared__ float comb[2][16][17];            // 2.1 KB
    int tid = threadIdx.x;
    int lane = tid & 63;
    int wave = tid >> 6;
    int b0 = blockIdx.x * 32;

    if (tid < 45) {
        float a = 0.f, b = 0.f;
#pragma unroll
        for (int c = 0; c < 8; ++c) {
            eb1[tid * 8 + c] = a; a += sums1[tid * 8 + c];
            eb2[tid * 8 + c] = b; b += sums2[tid * 8 + c];
        }
    }
    __syncthreads();

    for (int i = tid; i < 135 * 32; i += 128) {
        int fj = i >> 5, r = i & 31;
        int f = fj / 3, j = fj - 3 * f;
        int b = b0 + r;
        int L = (j == 0) ? 32 : (j == 1) ? 128 : 512;
        const float* c1 = cs_t + f * 8192;
        const float* c2 = cs2_t + f * 8192;
        float a1 = c1[b] + eb1[f * 8 + (b >> 10)];
        float a2 = c2[b] + eb2[f * 8 + (b >> 10)];
        float p1 = 0.f, p2 = 0.f;
        if (b >= L) {
            int ix = b - L;
            p1 = c1[ix] + eb1[f * 8 + (ix >> 10)];
            p2 = c2[ix] + eb2[f * 8 + (ix >> 10)];
        }
        float cnt = (float)((b + 1 < L) ? (b + 1) : L);
        float m = (a1 - p1) / cnt;
        float v = (a2 - p2) / cnt - m * m;
        int d0 = f * 6 + j * 2;
        Es[r * ESTRIDE + d0]     = f2bf(m);
        Es[r * ESTRIDE + d0 + 1] = f2bf(v);
    }
    for (int i = tid; i < 32 * 18; i += 128) {
        int r = i / 18, d = 270 + i % 18;
        Es[r * ESTRIDE + d] = 0;
    }
    __syncthreads();

    const int quad = lane >> 4;
    const int mrow = lane & 15;

    f32x4 acc = f32x4{0.f, 0.f, 0.f, 0.f};
    const unsigned short* erow = Es + (wave * 16 + mrow) * ESTRIDE + quad * 8;
    const unsigned short* wrow = Wb + (size_t)mrow * 2336 + 2048 + quad * 8;
#pragma unroll
    for (int k = 0; k < 288; k += 32) {
        s16x8 a = *(const s16x8*)(erow + k);
        s16x8 b = *(const s16x8*)(wrow + k);
        acc = __builtin_amdgcn_mfma_f32_16x16x32_bf16(a, b, acc, 0, 0, 0);
    }
#pragma unroll
    for (int r = 0; r < 4; ++r) comb[wave][quad * 4 + r][mrow] = acc[r];
    __syncthreads();

    if (tid < 32) {
        int w = tid >> 4, r = tid & 15;
        int grow = b0 + w * 16 + r;
        float lg[10];
        float mx = -1e30f;
#pragma unroll
        for (int c = 0; c < 10; ++c) {
            lg[c] = comb[w][r][c] + linp[(size_t)grow * 10 + c] + b_lin[c];
            mx = fmaxf(mx, lg[c]);
        }
        float s = 0.f;
#pragma unroll
        for (int c = 0; c < 10; ++c) { lg[c] = expf(lg[c] - mx); s += lg[c]; }
        float inv = 1.0f / s;
#pragma unroll
        for (int c = 0; c < 10; ++c) out[(size_t)grow * 10 + c] = lg[c] * inv;
    }
}

// ---------------- launch ----------------
extern "C" void kernel_launch(void* const* d_in, const int* in_sizes, int n_in,
                              void* d_out, int out_size, void* d_ws, size_t ws_size,
                              hipStream_t stream) {
    const float* x     = (const float*)d_in[0];   // (8192,1,2048)
    const float* W_ih  = (const float*)d_in[1];   // (2048,2048)
    // d_in[2] = W_hh unused: h0 == 0 so the recurrent term vanishes
    const float* b_ih  = (const float*)d_in[3];
    const float* b_hh  = (const float*)d_in[4];
    const float* W_lin = (const float*)d_in[5];   // (10, 2318)
    const float* b_lin = (const float*)d_in[6];
    float* out = (float*)d_out;

    char* ws = (char*)d_ws;
    unsigned short* xb  = (unsigned short*)(ws);                 // 33554432 B
    unsigned short* wb  = (unsigned short*)(ws + 33554432);      //  8388608 B
    float* pooled_t     = (float*)(ws + 41943040);               //  1474560 B (raw sums)
    float* linp         = (float*)(ws + 43417600);               //   327680 B
    float* cs_t         = (float*)(ws + 43745280);               //  1474560 B
    float* cs2_t        = (float*)(ws + 45219840);               //  1474560 B
    unsigned short* wlb = (unsigned short*)(ws + 46694400);      //    74752 B
    float* sums1        = (float*)(ws + 46769152);               //     1440 B
    float* sums2        = (float*)(ws + 46770592);               //     1440 B (~46.8 MB)

    cvtprep_kernel<<<21066, 256, 0, stream>>>(x, W_ih, W_lin, xb, wb, wlb, pooled_t);
    gemm_tanh_kernel<<<256, 512, 0, stream>>>(xb, wb, b_ih, b_hh, wlb, pooled_t, linp);
    scan_kernel<<<360, 256, 0, stream>>>(pooled_t, cs_t, cs2_t, sums1, sums2);
    final_kernel<<<256, 128, 0, stream>>>(cs_t, cs2_t, sums1, sums2, wlb, linp, b_lin, out);
}